// Round 8
// baseline (43.272 us; speedup 1.0000x reference)
//
#include <hip/hip_runtime.h>

#define B 4
#define P 1024
#define M 12
#define N 256
#define L 512
#define D 256
#define DC 256
#define FEA 1064          // 2*D + 20 + 20 + 2*DC
#define ROWS (B * P * M)  // 49152
#define NBLK 2048         // persistent blocks
#define NWAV (NBLK * 4)   // 8192 waves
#define TRIPS (ROWS / NWAV) // 6 exactly — uniform trip count, no tail

typedef float f32x4 __attribute__((ext_vector_type(4)));

struct Desc {
    int4 sel;
    int px, py, pz, pw;   // pos[sel.x], pos[sel.y], pos[sel.z], pos[sel.w]
    int b, branch;
};

__device__ __forceinline__ Desc load_desc(int row,
                                          const int* __restrict__ rel,
                                          const int* __restrict__ pinfo) {
    Desc d;
    d.b = row / (P * M);
    d.branch = (row % M) >> 2;
    d.sel = *reinterpret_cast<const int4*>(rel + (size_t)row * 4);
    const int* pb = pinfo + d.b * N * 6;   // pos[n] = pb[n*6]
    d.px = pb[d.sel.x * 6];
    d.py = pb[d.sel.y * 6];
    d.pz = pb[d.sel.z * 6];
    d.pw = pb[d.sel.w * 6];
    return d;
}

__global__ __launch_bounds__(256) void fused_kernel(
    const int* __restrict__ rel,    // [B,P,M,4]
    const int* __restrict__ pinfo,  // [B,N,6]
    const float* __restrict__ gf,   // [B,N,D]
    const float* __restrict__ cf,   // [B,L,DC]
    const float* __restrict__ dw,   // [20,20]
    const float* __restrict__ sw,   // [20,20]
    float* __restrict__ out)        // [ROWS*FEA] fea ++ [ROWS] mask
{
    const int lane  = threadIdx.x & 63;
    const int gwave = (blockIdx.x * 256 + threadIdx.x) >> 6;

    int r   = gwave;
    int row = __builtin_amdgcn_readfirstlane(r);
    Desc d  = load_desc(row, rel, pinfo);       // prologue: first row's descriptor

    #pragma unroll 1
    for (int it = 0; it < TRIPS; ++it) {
        // ---- current row: offsets (ALU only; all inputs already loaded) ----
        const bool logical = (d.branch == 2);
        const float zf = ((d.sel.x + d.sel.y + d.sel.z + d.sel.w) > 0) ? 1.0f : 0.0f;
        const int ibn    = (d.branch == 0) ? d.sel.z : d.sel.w;
        const int pos_ib = (d.branch == 0) ? d.pz : d.pw;
        const int delta  = d.px - pos_ib;        // pos_ia == pos[sel.x] == px
        const int u   = delta & 511;             // jnp.mod(delta, 512)
        const int d2  = (u == 0) ? 0 : (32 - __clz(u));
        const int idx = (delta < 0) ? (10 - d2) : (10 + d2);
        const int cb  = d.b * L * DC;

        const int offA = __builtin_amdgcn_readfirstlane((d.b * N + d.sel.x) * D);
        const int offB = __builtin_amdgcn_readfirstlane((d.b * N + ibn) * D);
        const int offE = __builtin_amdgcn_readfirstlane(idx * 20);
        const int off0 = __builtin_amdgcn_readfirstlane(cb + d.px * DC);
        const int off1 = __builtin_amdgcn_readfirstlane(cb + d.py * DC);
        const int off2 = __builtin_amdgcn_readfirstlane(cb + d.pz * DC);
        const int off3 = __builtin_amdgcn_readfirstlane(cb + d.pw * DC);

        const f32x4* gA  = reinterpret_cast<const f32x4*>(gf + offA);
        const f32x4* gB  = reinterpret_cast<const f32x4*>(gf + offB);
        const f32x4* dwr = reinterpret_cast<const f32x4*>(dw + offE);
        const f32x4* swr = reinterpret_cast<const f32x4*>(sw + offE);
        const f32x4* c0  = reinterpret_cast<const f32x4*>(cf + off0);
        const f32x4* c1  = reinterpret_cast<const f32x4*>(cf + off1);
        const f32x4* c2  = reinterpret_cast<const f32x4*>(cf + off2);
        const f32x4* c3  = reinterpret_cast<const f32x4*>(cf + off3);

        // ---- issue all gathers for current row ----
        f32x4 v0 = gA[lane];                        // f4[0,64)   rep A
        f32x4 v1 = gB[lane];                        // f4[64,128) rep B
        f32x4 v2, v3, v4 = {0.f, 0.f, 0.f, 0.f};
        if (lane < 5)       v2 = dwr[lane];
        else if (lane < 10) v2 = swr[lane - 5];
        else {              v2 = c0[lane - 10]; if (logical) v2 += c1[lane - 10]; }
        if (lane < 10) {    v3 = c0[54 + lane]; if (logical) v3 += c1[54 + lane]; }
        else {              v3 = c2[lane - 10]; if (logical) v3 += c3[lane - 10]; }
        if (lane < 10) {    v4 = c2[54 + lane]; if (logical) v4 += c3[54 + lane]; }

        // ---- prefetch next row's descriptor (overlaps gathers + stores) ----
        const int rn   = r + NWAV;
        const int rown = __builtin_amdgcn_readfirstlane((rn < ROWS) ? rn : row);
        Desc dn = load_desc(rown, rel, pinfo);

        // ---- scale + store current row ----
        v0 *= zf; v1 *= zf; v2 *= zf; v3 *= zf; v4 *= zf;

        f32x4* orow = reinterpret_cast<f32x4*>(out + (size_t)row * FEA);
        orow[lane]       = v0;
        orow[64 + lane]  = v1;
        orow[128 + lane] = v2;
        orow[192 + lane] = v3;
        if (lane < 10) orow[256 + lane] = v4;

        if (lane == 0) {
            const bool rm = (d.sel.x > 0) || (d.sel.y > 0) || (d.sel.z > 0) || (d.sel.w > 0);
            out[(size_t)ROWS * FEA + row] = rm ? 1.0f : 0.0f;
        }

        // ---- rotate pipeline ----
        d = dn; r = rn; row = rown;
    }
}

extern "C" void kernel_launch(void* const* d_in, const int* in_sizes, int n_in,
                              void* d_out, int out_size, void* d_ws, size_t ws_size,
                              hipStream_t stream) {
    const int*   rel   = (const int*)d_in[0];
    const int*   pinfo = (const int*)d_in[1];
    const float* gf    = (const float*)d_in[2];
    const float* cf    = (const float*)d_in[3];
    const float* dw    = (const float*)d_in[4];
    const float* sw    = (const float*)d_in[5];
    float* out = (float*)d_out;

    fused_kernel<<<NBLK, 256, 0, stream>>>(rel, pinfo, gf, cf, dw, sw, out);
}

// Round 9
// 42.758 us; speedup vs baseline: 1.0120x; 1.0120x over previous
//
#include <hip/hip_runtime.h>

#define B 4
#define P 1024
#define M 12
#define N 256
#define L 512
#define D 256
#define DC 256
#define FEA 1064          // 2*D + 20 + 20 + 2*DC
#define ROWS (B * P * M)  // 49152
#define NBLK 2048         // persistent blocks
#define NXCD 8

typedef float f32x4 __attribute__((ext_vector_type(4)));

__global__ __launch_bounds__(256) void fused_kernel(
    const int* __restrict__ rel,    // [B,P,M,4]
    const int* __restrict__ pinfo,  // [B,N,6]
    const float* __restrict__ gf,   // [B,N,D]
    const float* __restrict__ cf,   // [B,L,DC]
    const float* __restrict__ dw,   // [20,20]
    const float* __restrict__ sw,   // [20,20]
    float* __restrict__ out)        // [ROWS*FEA] fea ++ [ROWS] mask
{
    // Chunked XCD swizzle: blocks dispatch round-robin across 8 XCDs, so give
    // blocks with bid%8==x a CONTIGUOUS range of rows -> each XCD's gather
    // working set stays within ~1 batch (3MB) and fits its 4MiB L2.
    const int bid  = blockIdx.x;
    const int sbid = (bid & (NXCD - 1)) * (NBLK / NXCD) + (bid >> 3);

    const int lane  = threadIdx.x & 63;
    const int gwave = (sbid * 256 + threadIdx.x) >> 6;
    const int nwav  = NBLK * 4;

    for (int r = gwave; r < ROWS; r += nwav) {
        const int row = __builtin_amdgcn_readfirstlane(r);

        // ---- descriptor math, wave-redundant (all L1-hit tiny loads) ----
        const int b = row / (P * M);
        const int m = row % M;
        const int branch = m >> 2;

        const int4 sel = *reinterpret_cast<const int4*>(rel + (size_t)row * 4);
        const float zf = ((sel.x + sel.y + sel.z + sel.w) > 0) ? 1.0f : 0.0f;
        const int ia = sel.x;
        const int ib = (branch == 0) ? sel.z : sel.w;
        const bool logical = (branch == 2);

        const int* pbase = pinfo + b * N * 6;     // pos[n] = pbase[n*6]
        const int pos_ia = pbase[ia * 6];
        const int pos_ib = pbase[ib * 6];
        const int delta = pos_ia - pos_ib;
        const int u = delta & 511;                 // jnp.mod(delta, 512)
        const int d2 = (u == 0) ? 0 : (32 - __clz(u));
        const int idx = (delta < 0) ? (10 - d2) : (10 + d2);

        const int s0 = pbase[sel.x * 6];
        const int s2 = pbase[sel.z * 6];
        const int s1 = logical ? pbase[sel.y * 6] : 0;
        const int s3 = logical ? pbase[sel.w * 6] : 0;

        const int cb = b * L * DC;
        // Force computed offsets into SGPRs → scalar base + lane offset addressing.
        const int offA  = __builtin_amdgcn_readfirstlane((b * N + ia) * D);
        const int offB  = __builtin_amdgcn_readfirstlane((b * N + ib) * D);
        const int offE  = __builtin_amdgcn_readfirstlane(idx * 20);
        const int off0  = __builtin_amdgcn_readfirstlane(cb + s0 * DC);
        const int off1  = __builtin_amdgcn_readfirstlane(cb + s1 * DC);
        const int off2  = __builtin_amdgcn_readfirstlane(cb + s2 * DC);
        const int off3  = __builtin_amdgcn_readfirstlane(cb + s3 * DC);

        const f32x4* gA  = reinterpret_cast<const f32x4*>(gf + offA);
        const f32x4* gB  = reinterpret_cast<const f32x4*>(gf + offB);
        const f32x4* dwr = reinterpret_cast<const f32x4*>(dw + offE);
        const f32x4* swr = reinterpret_cast<const f32x4*>(sw + offE);
        const f32x4* c0  = reinterpret_cast<const f32x4*>(cf + off0);
        const f32x4* c1  = reinterpret_cast<const f32x4*>(cf + off1);
        const f32x4* c2  = reinterpret_cast<const f32x4*>(cf + off2);
        const f32x4* c3  = reinterpret_cast<const f32x4*>(cf + off3);

        // ---- gather: issue all loads before any store ----
        f32x4 v0 = gA[lane];                        // f4[0,64)   rep A
        f32x4 v1 = gB[lane];                        // f4[64,128) rep B
        f32x4 v2, v3, v4 = {0.f, 0.f, 0.f, 0.f};
        // f4[128,192): 5 emb + 5 semb + c0[0..53]
        if (lane < 5)       v2 = dwr[lane];
        else if (lane < 10) v2 = swr[lane - 5];
        else {              v2 = c0[lane - 10]; if (logical) v2 += c1[lane - 10]; }
        // f4[192,256): c0[54..63] + c2[0..53]
        if (lane < 10) {    v3 = c0[54 + lane]; if (logical) v3 += c1[54 + lane]; }
        else {              v3 = c2[lane - 10]; if (logical) v3 += c3[lane - 10]; }
        // f4[256,266): c2[54..63] (lanes 0..9 only)
        if (lane < 10) {    v4 = c2[54 + lane]; if (logical) v4 += c3[54 + lane]; }

        v0 *= zf; v1 *= zf; v2 *= zf; v3 *= zf; v4 *= zf;

        f32x4* orow = reinterpret_cast<f32x4*>(out + (size_t)row * FEA);
        orow[lane]       = v0;
        orow[64 + lane]  = v1;
        orow[128 + lane] = v2;
        orow[192 + lane] = v3;
        if (lane < 10) orow[256 + lane] = v4;

        if (lane == 0) {
            const bool rm = (sel.x > 0) || (sel.y > 0) || (sel.z > 0) || (sel.w > 0);
            out[(size_t)ROWS * FEA + row] = rm ? 1.0f : 0.0f;
        }
    }
}

extern "C" void kernel_launch(void* const* d_in, const int* in_sizes, int n_in,
                              void* d_out, int out_size, void* d_ws, size_t ws_size,
                              hipStream_t stream) {
    const int*   rel   = (const int*)d_in[0];
    const int*   pinfo = (const int*)d_in[1];
    const float* gf    = (const float*)d_in[2];
    const float* cf    = (const float*)d_in[3];
    const float* dw    = (const float*)d_in[4];
    const float* sw    = (const float*)d_in[5];
    float* out = (float*)d_out;

    fused_kernel<<<NBLK, 256, 0, stream>>>(rel, pinfo, gf, cf, dw, sw, out);
}

// Round 10
// 39.403 us; speedup vs baseline: 1.0982x; 1.0851x over previous
//
#include <hip/hip_runtime.h>

#define B 4
#define P 1024
#define M 12
#define N 256
#define L 512
#define D 256
#define DC 256
#define FEA 1064          // 2*D + 20 + 20 + 2*DC
#define ROWS (B * P * M)  // 49152

typedef float f32x4 __attribute__((ext_vector_type(4)));

__global__ __launch_bounds__(256) void fused_kernel(
    const int* __restrict__ rel,    // [B,P,M,4]
    const int* __restrict__ pinfo,  // [B,N,6]
    const float* __restrict__ gf,   // [B,N,D]
    const float* __restrict__ cf,   // [B,L,DC]
    const float* __restrict__ dw,   // [20,20]
    const float* __restrict__ sw,   // [20,20]
    float* __restrict__ out)        // [ROWS*FEA] fea ++ [ROWS] mask
{
    const int lane = threadIdx.x & 63;
    const int wid  = threadIdx.x >> 6;
    // One row per wave; no loop -> no inter-iteration vmcnt coupling; wave
    // retires with stores in flight and its slot refills with a fresh wave.
    const int row = __builtin_amdgcn_readfirstlane(blockIdx.x * 4 + wid);

    // ---- descriptor math, wave-redundant (all L1-hit tiny loads) ----
    const int b = row / (P * M);
    const int m = row % M;
    const int branch = m >> 2;

    const int4 sel = *reinterpret_cast<const int4*>(rel + (size_t)row * 4);
    const float zf = ((sel.x + sel.y + sel.z + sel.w) > 0) ? 1.0f : 0.0f;
    const int ia = sel.x;
    const int ib = (branch == 0) ? sel.z : sel.w;
    const bool logical = (branch == 2);

    const int* pbase = pinfo + b * N * 6;     // pos[n] = pbase[n*6]
    const int pos_ia = pbase[ia * 6];
    const int pos_ib = pbase[ib * 6];
    const int delta = pos_ia - pos_ib;
    const int u = delta & 511;                 // jnp.mod(delta, 512)
    const int d2 = (u == 0) ? 0 : (32 - __clz(u));
    const int idx = (delta < 0) ? (10 - d2) : (10 + d2);

    const int s0 = pbase[sel.x * 6];
    const int s2 = pbase[sel.z * 6];
    const int s1 = logical ? pbase[sel.y * 6] : 0;
    const int s3 = logical ? pbase[sel.w * 6] : 0;

    const int cb = b * L * DC;
    // Force computed offsets into SGPRs → scalar base + lane offset addressing.
    const int offA  = __builtin_amdgcn_readfirstlane((b * N + ia) * D);
    const int offB  = __builtin_amdgcn_readfirstlane((b * N + ib) * D);
    const int offE  = __builtin_amdgcn_readfirstlane(idx * 20);
    const int off0  = __builtin_amdgcn_readfirstlane(cb + s0 * DC);
    const int off1  = __builtin_amdgcn_readfirstlane(cb + s1 * DC);
    const int off2  = __builtin_amdgcn_readfirstlane(cb + s2 * DC);
    const int off3  = __builtin_amdgcn_readfirstlane(cb + s3 * DC);

    const f32x4* gA  = reinterpret_cast<const f32x4*>(gf + offA);
    const f32x4* gB  = reinterpret_cast<const f32x4*>(gf + offB);
    const f32x4* dwr = reinterpret_cast<const f32x4*>(dw + offE);
    const f32x4* swr = reinterpret_cast<const f32x4*>(sw + offE);
    const f32x4* c0  = reinterpret_cast<const f32x4*>(cf + off0);
    const f32x4* c1  = reinterpret_cast<const f32x4*>(cf + off1);
    const f32x4* c2  = reinterpret_cast<const f32x4*>(cf + off2);
    const f32x4* c3  = reinterpret_cast<const f32x4*>(cf + off3);

    // ---- gather: issue all loads before any store ----
    f32x4 v0 = gA[lane];                        // f4[0,64)   rep A
    f32x4 v1 = gB[lane];                        // f4[64,128) rep B
    f32x4 v2, v3, v4 = {0.f, 0.f, 0.f, 0.f};
    // f4[128,192): 5 emb + 5 semb + c0[0..53]
    if (lane < 5)       v2 = dwr[lane];
    else if (lane < 10) v2 = swr[lane - 5];
    else {              v2 = c0[lane - 10]; if (logical) v2 += c1[lane - 10]; }
    // f4[192,256): c0[54..63] + c2[0..53]
    if (lane < 10) {    v3 = c0[54 + lane]; if (logical) v3 += c1[54 + lane]; }
    else {              v3 = c2[lane - 10]; if (logical) v3 += c3[lane - 10]; }
    // f4[256,266): c2[54..63] (lanes 0..9 only)
    if (lane < 10) {    v4 = c2[54 + lane]; if (logical) v4 += c3[54 + lane]; }

    v0 *= zf; v1 *= zf; v2 *= zf; v3 *= zf; v4 *= zf;

    f32x4* orow = reinterpret_cast<f32x4*>(out + (size_t)row * FEA);
    orow[lane]       = v0;
    orow[64 + lane]  = v1;
    orow[128 + lane] = v2;
    orow[192 + lane] = v3;
    if (lane < 10) orow[256 + lane] = v4;

    if (lane == 0) {
        const bool rm = (sel.x > 0) || (sel.y > 0) || (sel.z > 0) || (sel.w > 0);
        out[(size_t)ROWS * FEA + row] = rm ? 1.0f : 0.0f;
    }
}

extern "C" void kernel_launch(void* const* d_in, const int* in_sizes, int n_in,
                              void* d_out, int out_size, void* d_ws, size_t ws_size,
                              hipStream_t stream) {
    const int*   rel   = (const int*)d_in[0];
    const int*   pinfo = (const int*)d_in[1];
    const float* gf    = (const float*)d_in[2];
    const float* cf    = (const float*)d_in[3];
    const float* dw    = (const float*)d_in[4];
    const float* sw    = (const float*)d_in[5];
    float* out = (float*)d_out;

    fused_kernel<<<ROWS / 4, 256, 0, stream>>>(rel, pinfo, gf, cf, dw, sw, out);
}